// Round 1
// baseline (464.145 us; speedup 1.0000x reference)
//
#include <hip/hip_runtime.h>

// Problem constants (match reference): K=4, B=4096, T=32, D=128
constexpr int K = 4;
constexpr int B = 4096;   // power of two: kb>>12 = k
constexpr int T = 32;
constexpr int D = 128;
constexpr int TT = T * T;   // 1024 pairs per anchor
constexpr int TD = T * D;   // 4096 floats per anchor's nbr_embed

typedef float f4 __attribute__((ext_vector_type(4)));

__device__ __forceinline__ float dot4(f4 a, f4 b) {
    return a.x * b.x + a.y * b.y + a.z * b.z + a.w * b.w;
}

// butterfly sum across each 32-lane half of the wave-64 (xor masks <=16
// never cross the half boundary)
__device__ __forceinline__ float hreduce32(float p) {
    #pragma unroll
    for (int m = 16; m >= 1; m >>= 1) p += __shfl_xor(p, m, 64);
    return p;
}

// 128 B of wave-private LDS per anchor: the only cross-lane exchange that
// can't ride on shfl/ballot. Same-wave LDS is in-order -> no barrier ever.
struct __align__(16) WaveSh { float nsim[T]; };

// BARRIER-FREE: one wave64 per (k,b) anchor, 4 anchors per 256-thread block.
// Rationale: the previous block-per-anchor kernel had two __syncthreads,
// each compiling to `s_waitcnt vmcnt(0) lgkmcnt(0); s_barrier` — the second
// one drains the full 16KB nbr store queue per tiny block, holding effective
// write BW to ~3 TB/s vs the ~6.2 TB/s fill yardstick. Here nothing ever
// waits on a store.
__global__ __launch_bounds__(256) void distance_layer_kernel(
    const float* __restrict__ semb,     // [K,B,D]
    const int*   __restrict__ slabels,  // [K,B]
    const int*   __restrict__ topk,     // [K,B,T]
    float* __restrict__ pos,            // [K,B,T,T]
    float* __restrict__ neg,            // [K,B,T,T]
    float* __restrict__ maskf,          // [K,B,T,T] (bool as 0.0/1.0)
    float* __restrict__ nbr)            // [K,B,T,D]
{
    const int tid  = threadIdx.x;
    const int wid  = tid >> 6;          // wave id within block = anchor slot
    const int l    = tid & 63;          // lane
    const int half = l >> 5;            // 0: even rows, 1: odd rows
    const int d4   = l & 31;            // float4 column within the D=128 row

    const int kb = blockIdx.x * 4 + wid;
    const int k  = kb >> 12;

    __shared__ WaveSh sh[4];
    WaveSh& w = sh[wid];

    // ---- wave-local staging: indices + same-label ballot ---------------
    const int my_label = slabels[kb];
    const int idx_l    = topk[kb * T + d4];   // lane l holds idx of row (l&31)
    const int same_l   = (slabels[(k << 12) + idx_l] == my_label) ? 1 : 0;
    // low 32 bits: bit r = same[r] (both halves agree, truncation is safe)
    const unsigned mask = (unsigned)__ballot(same_l);

    const f4* semb4 = reinterpret_cast<const f4*>(semb + (size_t)k * B * D);
    f4*       nbr4  = reinterpret_cast<f4*>(nbr + (size_t)kb * TD);
    const f4  a     = reinterpret_cast<const f4*>(semb + (size_t)kb * D)[d4];

    // ---- gather + nsim: 2 rows per step (one per half), 8-deep MLP -----
    #pragma unroll
    for (int g = 0; g < 2; ++g) {
        int ridx[8];
        #pragma unroll
        for (int j = 0; j < 8; ++j)
            ridx[j] = __shfl(idx_l, 16 * g + 2 * j + half, 64);

        f4 sv[8];
        #pragma unroll
        for (int j = 0; j < 8; ++j)
            sv[j] = semb4[(size_t)ridx[j] * (D / 4) + d4];

        #pragma unroll
        for (int j = 0; j < 8; ++j) {
            const int row = 16 * g + 2 * j + half;
            nbr4[row * (D / 4) + d4] = sv[j];           // fire-and-forget
            const float p = hreduce32(dot4(a, sv[j]));  // full sum in all lanes
            if (d4 == 0) w.nsim[row] = p;               // lane0 -> even, lane32 -> odd
        }
    }

    // ---- pair grid: 1024 (s,d) pairs, 16 per lane as 4x float4 ---------
    // flat pair index = (64*i + l)*4 + j  ->  s = 8i + (l>>3), d = (l&7)*4 + j
    const int d0 = (l & 7) * 4;
    const f4 ndv = *reinterpret_cast<const f4*>(&w.nsim[d0]); // in-wave LDS, ordered
    const unsigned md = (mask >> d0) & 0xFu;
    const int b0 =  md       & 1;
    const int b1 = (md >> 1) & 1;
    const int b2 = (md >> 2) & 1;
    const int b3 = (md >> 3) & 1;

    f4* pos4  = reinterpret_cast<f4*>(pos   + (size_t)kb * TT);
    f4* neg4  = reinterpret_cast<f4*>(neg   + (size_t)kb * TT);
    f4* mask4 = reinterpret_cast<f4*>(maskf + (size_t)kb * TT);

    #pragma unroll
    for (int i = 0; i < 4; ++i) {
        const int   s  = 8 * i + (l >> 3);
        const int   ss = (mask >> s) & 1;
        const float ps = w.nsim[s];

        const int m0 = ss & (b0 ^ 1);
        const int m1 = ss & (b1 ^ 1);
        const int m2 = ss & (b2 ^ 1);
        const int m3 = ss & (b3 ^ 1);

        f4 pv, nv, mv;
        pv.x = m0 ? ps : 0.0f;  nv.x = m0 ? ndv.x : 0.0f;  mv.x = (float)m0;
        pv.y = m1 ? ps : 0.0f;  nv.y = m1 ? ndv.y : 0.0f;  mv.y = (float)m1;
        pv.z = m2 ? ps : 0.0f;  nv.z = m2 ? ndv.z : 0.0f;  mv.z = (float)m2;
        pv.w = m3 ? ps : 0.0f;  nv.w = m3 ? ndv.w : 0.0f;  mv.w = (float)m3;

        pos4 [64 * i + l] = pv;   // contiguous 1KB per wave per instruction
        neg4 [64 * i + l] = nv;
        mask4[64 * i + l] = mv;
    }
}

extern "C" void kernel_launch(void* const* d_in, const int* in_sizes, int n_in,
                              void* d_out, int out_size, void* d_ws, size_t ws_size,
                              hipStream_t stream) {
    const float* semb    = (const float*)d_in[0];
    const int*   slabels = (const int*)d_in[1];
    const int*   topk    = (const int*)d_in[2];

    float* out = (float*)d_out;
    const size_t KBTT = (size_t)K * B * T * T;   // 16,777,216
    float* pos   = out;
    float* neg   = out + KBTT;
    float* maskf = out + 2 * KBTT;
    float* nbr   = out + 3 * KBTT;

    distance_layer_kernel<<<dim3(K * B / 4), dim3(256), 0, stream>>>(
        semb, slabels, topk, pos, neg, maskf, nbr);
}